// Round 2
// 3408.121 us; speedup vs baseline: 1.4782x; 1.4782x over previous
//
#include <hip/hip_runtime.h>
#include <hip/hip_bf16.h>

#define Bz 32
#define Tz 1024
#define Iz 64
#define Hz 512
#define Az 16
#define NB 16   // scan blocks: block owns 32 cols; wave w owns k-slice [64w,64w+64)

// d_out layout (FP32 elems): out [B,T,A] | hn [1,B,H] | rnn_out [B,T,H]
#define OFF_HN  (Bz*Tz*Az)
#define OFF_RNN (OFF_HN + Bz*Hz)

typedef unsigned short u16;
typedef unsigned int u32;
typedef unsigned long long u64;
typedef __attribute__((ext_vector_type(8))) unsigned short u16x8;
typedef __attribute__((ext_vector_type(8))) __bf16 bf16x8;
typedef __attribute__((ext_vector_type(4))) float f32x4;
typedef __attribute__((ext_vector_type(2))) float f32x2;

// ws layout (bytes)
#define WS_FLAGS 0x00000u   // int[1025*16] = 65,600 B (zeroed each launch)
#define WS_RING  0x21000u   // u16[4][32][512] = 131072 B
#define WS_WHH   0x41000u   // u16[512*512] bf16 = 512 KB
#define WS_WIH   0xC1000u   // u16[64*512] bf16 = 64 KB
#define WS_W1T   0xD1000u   // u16[512*512] bf16 [n][k]
#define WS_ZERO  0x11000u   // memset span: covers flags only

__device__ __forceinline__ u16 f2bf(float f) {
  union { float f; unsigned int i; } x; x.f = f;
  unsigned int r = (x.i + 0x7FFFu + ((x.i >> 16) & 1u)) >> 16;
  return (u16)r;
}
__device__ __forceinline__ float bf2f(u16 u) {
  union { unsigned int i; float f; } x; x.i = ((unsigned int)u) << 16; return x.f;
}
__device__ __forceinline__ float sigmoidf_(float z) {
  return 1.0f / (1.0f + __expf(-z));
}

// ---------------------------------------------------------------------------
// Prep: fp32 -> bf16 copies (w_hh, w_ih layout-preserved; fc1_w transposed)
// ---------------------------------------------------------------------------
__global__ void prep_kernel(const float* __restrict__ whh,
                            const float* __restrict__ wih,
                            const float* __restrict__ w1,
                            u16* __restrict__ whh_bf,
                            u16* __restrict__ wih_bf,
                            u16* __restrict__ w1t_bf) {
  int idx = blockIdx.x * 256 + threadIdx.x;
  if (idx < 262144) {
    whh_bf[idx] = f2bf(whh[idx]);
  } else if (idx < 294912) {
    int i = idx - 262144;
    wih_bf[i] = f2bf(wih[i]);
  } else if (idx < 557056) {
    int j = idx - 294912;
    int n = j >> 9, k = j & 511;
    w1t_bf[n * Hz + k] = f2bf(w1[k * Hz + n]);  // [n][k] <- [k][n]
  }
}

// ---------------------------------------------------------------------------
// Scan R8: 16 blocks x 512 thr (8 waves). Block b owns cols [32b, 32b+32).
// K-split: wave w computes the k-slice [64w, 64w+64) contribution for the
// whole 32x32 output tile (2 row-tiles x 2 col-tiles x 2 k-chunks = 8 MFMA),
// then cross-wave LDS reduction + sigmoid + ring store.
// Rationale (R8 theory): old design needed 32 live u64 h-loads/lane ->
// register-starved scheduling serialized them into multiple L3 round trips.
// Now 8 u64/lane (one pipelined RT) and per-wave polls of only 2 source
// flags. Union of the 8 waves' polls covers all 16 flags, so the proven
// all-RELAXED convoy/ring-safety argument is unchanged:
//   producer: ring atomic-stores -> __syncthreads (drains vmcnt) ->
//   relaxed flag store -> plain output stores.
//   consumer: relaxed flag poll (exit only after load RETURNS 1) -> loads
//   issued strictly later -> MFMA.
// MFMA 16x16x32 bf16 (HW-proven): A m=lane&15,k=q*8+j; B n=lane&15,k=q*8+j;
//                                 C/D col=lane&15, row=q*4+reg.
// ---------------------------------------------------------------------------
__global__ __launch_bounds__(512, 1) void rnn_scan_kernel(
    const float* __restrict__ inp,   // [B][T][I] fp32
    const float* __restrict__ hn,    // [B][H] fp32
    const u16* __restrict__ whh_bf,  // [k=H][n=H] bf16
    const u16* __restrict__ wih_bf,  // [i=I][n=H] bf16
    float* __restrict__ out_rnn,     // [B][T][H] fp32
    float* __restrict__ out_hn,      // [B][H] fp32
    int* __restrict__ flags,         // [1025][NB] (zeroed)
    u16* __restrict__ hbuf)          // [4][B][H] bf16 ring
{
  __shared__ float part[8 * 32 * 33];  // [wave][row][col pad33] = 33,792 B

  const int tid  = threadIdx.x;
  const int lane = tid & 63;
  const int w    = tid >> 6;      // wave 0..7 -> k-slice [64w, 64w+64)
  const int ln   = lane & 15;
  const int q    = lane >> 4;
  const int c0   = blockIdx.x * 32;
  const int k0   = w * 64;

  // Preload W_hh B-fragments for this wave's k-slice (one-time gathers)
  bf16x8 bhh[2][2];  // [col-tile][k-chunk]
#pragma unroll
  for (int ct = 0; ct < 2; ++ct)
#pragma unroll
    for (int kc = 0; kc < 2; ++kc) {
      u16x8 f;
#pragma unroll
      for (int j = 0; j < 8; ++j)
        f[j] = whh_bf[(k0 + kc * 32 + q * 8 + j) * Hz + c0 + ct * 16 + ln];
      bhh[ct][kc] = __builtin_bit_cast(bf16x8, f);
    }

  // Waves 0,1 additionally own the x-projection k-chunks (I=64 = 2 chunks)
  bf16x8 bih[2];     // [col-tile]
  if (w < 2) {
#pragma unroll
    for (int ct = 0; ct < 2; ++ct) {
      u16x8 f;
#pragma unroll
      for (int j = 0; j < 8; ++j)
        f[j] = wih_bf[(w * 32 + q * 8 + j) * Hz + c0 + ct * 16 + ln];
      bih[ct] = __builtin_bit_cast(bf16x8, f);
    }
  }

  const int orow = tid >> 4;       // 0..31  (output row)
  const int ocp  = tid & 15;       // col pair index
  const int ocol = c0 + ocp * 2;

  // Init ring slot 0 (own 32 cols, all 32 rows) — packed coherent u32 stores
  {
    u32 pk = (u32)f2bf(hn[orow * Hz + ocol]) |
             ((u32)f2bf(hn[orow * Hz + ocol + 1]) << 16);
    __hip_atomic_store((u32*)(hbuf + orow * Hz + ocol), pk, __ATOMIC_RELAXED,
                       __HIP_MEMORY_SCOPE_AGENT);
  }
  __syncthreads();
  if (tid == 0)
    __hip_atomic_store(&flags[blockIdx.x], 1, __ATOMIC_RELAXED,
                       __HIP_MEMORY_SCOPE_AGENT);

  for (int t = 0; t < Tz; ++t) {
    // Issue inp loads early (off critical path; only waves 0,1 need them)
    f32x4 xl0, xh0, xl1, xh1;
    if (w < 2) {
      const float* p0 = inp + ((size_t)(ln)      * Tz + t) * Iz + w * 32 + q * 8;
      const float* p1 = inp + ((size_t)(16 + ln) * Tz + t) * Iz + w * 32 + q * 8;
      xl0 = *(const f32x4*)p0; xh0 = *(const f32x4*)(p0 + 4);
      xl1 = *(const f32x4*)p1; xh1 = *(const f32x4*)(p1 + 4);
    }

    // Relaxed poll: this wave needs only its 2 source blocks {2w, 2w+1}
    {
      const int sb = 2 * w + (lane & 1);
      int got;
      do {
        got = __hip_atomic_load(&flags[t * NB + sb], __ATOMIC_RELAXED,
                                __HIP_MEMORY_SCOPE_AGENT);
      } while (!__all(got));
    }

    // Issue ALL 8 h-fragment loads up front (one pipelined L3 round trip)
    const u64* hb = (const u64*)hbuf + (size_t)(t & 3) * (Bz * Hz / 4);
    u64 hr[8];
#pragma unroll
    for (int rt = 0; rt < 2; ++rt)
#pragma unroll
      for (int kc = 0; kc < 2; ++kc) {
        const u64* p = hb + (size_t)(rt * 16 + ln) * (Hz / 4) + w * 16 +
                       kc * 8 + q * 2;
        hr[rt * 4 + kc * 2 + 0] = __hip_atomic_load(
            p, __ATOMIC_RELAXED, __HIP_MEMORY_SCOPE_AGENT);
        hr[rt * 4 + kc * 2 + 1] = __hip_atomic_load(
            p + 1, __ATOMIC_RELAXED, __HIP_MEMORY_SCOPE_AGENT);
      }

    f32x4 acc[2][2];
#pragma unroll
    for (int rt = 0; rt < 2; ++rt)
#pragma unroll
      for (int ct = 0; ct < 2; ++ct) acc[rt][ct] = (f32x4){0.f, 0.f, 0.f, 0.f};

    // x-projection MFMAs run in the latency shadow of the h-loads
    if (w < 2) {
      u16x8 ax0, ax1;
#pragma unroll
      for (int j = 0; j < 4; ++j) {
        ax0[j]     = f2bf(xl0[j]);
        ax0[4 + j] = f2bf(xh0[j]);
        ax1[j]     = f2bf(xl1[j]);
        ax1[4 + j] = f2bf(xh1[j]);
      }
#pragma unroll
      for (int ct = 0; ct < 2; ++ct) {
        acc[0][ct] = __builtin_amdgcn_mfma_f32_16x16x32_bf16(
            __builtin_bit_cast(bf16x8, ax0), bih[ct], acc[0][ct], 0, 0, 0);
        acc[1][ct] = __builtin_amdgcn_mfma_f32_16x16x32_bf16(
            __builtin_bit_cast(bf16x8, ax1), bih[ct], acc[1][ct], 0, 0, 0);
      }
    }

    // W_hh MFMAs for this wave's k-slice
#pragma unroll
    for (int kc = 0; kc < 2; ++kc)
#pragma unroll
      for (int rt = 0; rt < 2; ++rt) {
        u64 v[2] = {hr[rt * 4 + kc * 2], hr[rt * 4 + kc * 2 + 1]};
        bf16x8 af = __builtin_bit_cast(bf16x8, v);
#pragma unroll
        for (int ct = 0; ct < 2; ++ct)
          acc[rt][ct] = __builtin_amdgcn_mfma_f32_16x16x32_bf16(
              af, bhh[ct][kc], acc[rt][ct], 0, 0, 0);
      }

    // Partials -> LDS (pad 33 breaks bank aliasing)
#pragma unroll
    for (int rt = 0; rt < 2; ++rt)
#pragma unroll
      for (int ct = 0; ct < 2; ++ct)
#pragma unroll
        for (int r = 0; r < 4; ++r)
          part[w * 1056 + (rt * 16 + q * 4 + r) * 33 + ct * 16 + ln] =
              acc[rt][ct][r];
    __syncthreads();

    // Cross-wave reduce + sigmoid + packed coherent ring store
    float z0 = 0.f, z1 = 0.f;
#pragma unroll
    for (int ww = 0; ww < 8; ++ww) {
      z0 += part[ww * 1056 + orow * 33 + ocp * 2];
      z1 += part[ww * 1056 + orow * 33 + ocp * 2 + 1];
    }
    float h0 = sigmoidf_(z0), h1 = sigmoidf_(z1);
    u16* hbn = hbuf + ((t + 1) & 3) * (Bz * Hz);
    u32 pk = (u32)f2bf(h0) | ((u32)f2bf(h1) << 16);
    __hip_atomic_store((u32*)(hbn + orow * Hz + ocol), pk, __ATOMIC_RELAXED,
                       __HIP_MEMORY_SCOPE_AGENT);
    __syncthreads();  // drains every thread's ring stores (vmcnt) + guards part[]
    if (tid == 0)
      __hip_atomic_store(&flags[(t + 1) * NB + blockIdx.x], 1, __ATOMIC_RELAXED,
                         __HIP_MEMORY_SCOPE_AGENT);

    // Output stores AFTER the flag release — off the critical path
    f32x2 o2 = {h0, h1};
    *(f32x2*)(out_rnn + ((size_t)orow * Tz + t) * Hz + ocol) = o2;
    if (t == Tz - 1) *(f32x2*)(out_hn + orow * Hz + ocol) = o2;
  }
}

// ---------------------------------------------------------------------------
// FC head (unchanged, R3-lineage): 256 blocks x 256 thr; fc1 MFMA bf16
// (tile 128x128, BK=64); hidden via LDS; fc2 VALU-accumulated; fp32 in/out.
// ---------------------------------------------------------------------------
__global__ __launch_bounds__(256, 2) void fc_kernel(
    const float* __restrict__ X,  // [32768][512] fp32 (= rnn_out)
    const u16* __restrict__ w1t,  // [n=512][k=512] bf16
    const float* __restrict__ b1, // [512] fp32
    const float* __restrict__ w2, // [n=512][a=16] fp32
    const float* __restrict__ b2, // [16] fp32
    float* __restrict__ out)      // [32768][16] fp32
{
  __shared__ u16 smem[18432];     // 36 KB
  u16* As = smem;                 // [128][72]
  u16* Bs = smem + 9216;          // [128][72]
  u16* Ht = smem;                 // [128][136] (reused, 34816 B)

  const int tid  = threadIdx.x;
  const int lane = tid & 63;
  const int wv   = tid >> 6;
  const int ln   = lane & 15, q = lane >> 4;
  const int mq   = (wv & 1) * 64, nq = (wv >> 1) * 64;
  const size_t r0 = (size_t)blockIdx.x * 128;
  const int om = tid >> 1;          // output row 0..127
  const int oa = (tid & 1) * 8;     // output col half

  float oacc[8];
#pragma unroll
  for (int j = 0; j < 8; ++j) oacc[j] = 0.f;

  for (int nt = 0; nt < 4; ++nt) {
    const int n0 = nt * 128;
    f32x4 acc[4][4];
#pragma unroll
    for (int mi = 0; mi < 4; ++mi)
#pragma unroll
      for (int ni = 0; ni < 4; ++ni) acc[mi][ni] = (f32x4){0.f, 0.f, 0.f, 0.f};

    for (int kb = 0; kb < 8; ++kb) {
      const int K0 = kb * 64;
      __syncthreads();  // prior frag/Ht reads done before restaging
      for (int i = tid; i < 1024; i += 256) {
        int row = i >> 3, c = (i & 7) * 8;
        f32x4 lo = *(const f32x4*)(X + (r0 + row) * Hz + K0 + c);
        f32x4 hi = *(const f32x4*)(X + (r0 + row) * Hz + K0 + c + 4);
        u16x8 p;
#pragma unroll
        for (int j = 0; j < 4; ++j) { p[j] = f2bf(lo[j]); p[4 + j] = f2bf(hi[j]); }
        *(u16x8*)(As + row * 72 + c) = p;
      }
      for (int i = tid; i < 1024; i += 256) {
        int row = i >> 3, c = (i & 7) * 8;
        *(u16x8*)(Bs + row * 72 + c) =
            *(const u16x8*)(w1t + (size_t)(n0 + row) * Hz + K0 + c);
      }
      __syncthreads();
#pragma unroll
      for (int kt = 0; kt < 2; ++kt) {
        bf16x8 af[4], bfr[4];
#pragma unroll
        for (int mi = 0; mi < 4; ++mi)
          af[mi] = __builtin_bit_cast(
              bf16x8,
              *(const u16x8*)(As + (mq + mi * 16 + ln) * 72 + kt * 32 + q * 8));
#pragma unroll
        for (int ni = 0; ni < 4; ++ni)
          bfr[ni] = __builtin_bit_cast(
              bf16x8,
              *(const u16x8*)(Bs + (nq + ni * 16 + ln) * 72 + kt * 32 + q * 8));
#pragma unroll
        for (int mi = 0; mi < 4; ++mi)
#pragma unroll
          for (int ni = 0; ni < 4; ++ni)
            acc[mi][ni] = __builtin_amdgcn_mfma_f32_16x16x32_bf16(
                af[mi], bfr[ni], acc[mi][ni], 0, 0, 0);
      }
    }
    __syncthreads();  // MFMA frag reads done before Ht overwrite

    // hidden = relu(acc + b1) -> Ht bf16
#pragma unroll
    for (int ni = 0; ni < 4; ++ni) {
      float bb = b1[n0 + nq + ni * 16 + ln];
#pragma unroll
      for (int mi = 0; mi < 4; ++mi)
#pragma unroll
        for (int r = 0; r < 4; ++r) {
          float h = fmaxf(acc[mi][ni][r] + bb, 0.f);
          Ht[(mq + mi * 16 + q * 4 + r) * 136 + nq + ni * 16 + ln] = f2bf(h);
        }
    }
    __syncthreads();

    // fc2 partial over this n-slice into registers
    for (int n = 0; n < 128; ++n) {
      float hv = bf2f(Ht[om * 136 + n]);
      const float* w2p = w2 + (size_t)(n0 + n) * Az + oa;
#pragma unroll
      for (int j = 0; j < 8; ++j) oacc[j] += hv * w2p[j];
    }
  }

#pragma unroll
  for (int j = 0; j < 8; ++j)
    out[(r0 + om) * Az + oa + j] = sigmoidf_(oacc[j] + b2[oa + j]);
}

extern "C" void kernel_launch(void* const* d_in, const int* in_sizes, int n_in,
                              void* d_out, int out_size, void* d_ws, size_t ws_size,
                              hipStream_t stream) {
  // Permutation detection from in_sizes (insurance; proven harmless R6/R7)
  int idx_inp = 0, idx_hn = 1, idx_wih = 3, idx_b1 = 5, idx_w2 = 6, idx_b2 = 7;
  int amb1 = -1, amb2 = -1, found = 0;
  for (int i = 0; i < 8 && i < n_in; ++i) {
    switch (in_sizes[i]) {
      case 2097152: idx_inp = i; found |= 1; break;
      case 16384:   idx_hn  = i; found |= 2; break;
      case 32768:   idx_wih = i; found |= 4; break;
      case 512:     idx_b1  = i; found |= 8; break;
      case 8192:    idx_w2  = i; found |= 16; break;
      case 16:      idx_b2  = i; found |= 32; break;
      case 262144:  if (amb1 < 0) amb1 = i; else amb2 = i; break;
    }
  }
  int idx_whh = 2, idx_w1 = 4;  // dict-order fallback
  if (amb1 >= 0 && amb2 >= 0 && found == 63) {
    if (idx_b1 < idx_inp) { idx_w1 = amb1; idx_whh = amb2; }
    else                  { idx_whh = amb1; idx_w1 = amb2; }
  }

  const float* inp = (const float*)d_in[idx_inp];
  const float* hn  = (const float*)d_in[idx_hn];
  const float* whh = (const float*)d_in[idx_whh];
  const float* wih = (const float*)d_in[idx_wih];
  const float* w1  = (const float*)d_in[idx_w1];
  const float* b1  = (const float*)d_in[idx_b1];
  const float* w2  = (const float*)d_in[idx_w2];
  const float* b2  = (const float*)d_in[idx_b2];

  float* out     = (float*)d_out;
  float* out_hn  = out + OFF_HN;
  float* out_rnn = out + OFF_RNN;

  char* ws    = (char*)d_ws;
  int* flags  = (int*)(ws + WS_FLAGS);
  u16* hbuf   = (u16*)(ws + WS_RING);
  u16* whh_bf = (u16*)(ws + WS_WHH);
  u16* wih_bf = (u16*)(ws + WS_WIH);
  u16* w1t_bf = (u16*)(ws + WS_W1T);

  (void)hipMemsetAsync(d_ws, 0, WS_ZERO, stream);
  prep_kernel<<<dim3(2176), dim3(256), 0, stream>>>(whh, wih, w1,
                                                    whh_bf, wih_bf, w1t_bf);
  rnn_scan_kernel<<<dim3(NB), dim3(512), 0, stream>>>(
      inp, hn, whh_bf, wih_bf, out_rnn, out_hn, flags, hbuf);
  fc_kernel<<<dim3(256), dim3(256), 0, stream>>>(
      out_rnn, w1t_bf, b1, w2, b2, out);
}